// Round 11
// baseline (118.973 us; speedup 1.0000x reference)
//
#include <hip/hip_runtime.h>

#define IMG_H 512
#define IMG_W 512
#define PLANE (IMG_H * IMG_W)
#define NBATCH 64
#define NBINS 256
#define TSTRIP 16                               // rows per strip
#define HALF_W 256                              // columns per wave (half strip)
#define BLOCKS_PER_IMG 16
#define NBLOCKS (BLOCKS_PER_IMG * NBATCH)       // 1024 -> 4 blocks/CU, 16 waves/CU

#define GRAY(rr, gg, bb) (0.2989f * (rr) + 0.587f * (gg) + 0.114f * (bb))

// Single dispatch: strip LBP + LDS hist -> plain-store partial -> device-scope
// counter; last block per image (old%16==15, invariant to counter's initial
// garbage) sums partials, L2-normalizes, writes out. No second kernel.
__global__ __launch_bounds__(256) void lbp_fused_kernel(const float* __restrict__ x,
                                                        float* __restrict__ part,
                                                        unsigned int* __restrict__ cnt,
                                                        float* __restrict__ out) {
    __shared__ unsigned int lh[NBINS];
    const int tid = threadIdx.x;
    lh[tid] = 0u;                                // 256 threads == 256 bins
    __syncthreads();

    // XCD swizzle: XCD = blockIdx.x % 8; groups 128 blocks (8 images) per XCD.
    const int lin = blockIdx.x;                  // 0..1023
    const int sid = (lin & 7) * (NBLOCKS / 8) + (lin >> 3);
    const int b   = sid >> 4;                    // image 0..63
    const int bg  = sid & 15;                    // block-group 0..15

    const int wav   = tid >> 6;                  // 0..3
    const int lane  = tid & 63;
    const int strip = bg * 2 + (wav >> 1);       // 0..31 (16-row strip)
    const int half  = wav & 1;                   // 0 = cols 0..255, 1 = 256..511
    const int y0    = strip * TSTRIP;

    const float* rP = x + (size_t)b * 3 * PLANE;
    const float* gP = rP + PLANE;
    const float* bP = rP + 2 * PLANE;
    const int    cx = half * HALF_W + 4 * lane;  // lane's first column

    // arr[0]=left neighbor (col cx-1), arr[1..4]=cols cx..cx+3, arr[5]=right (col cx+4)
    float t_[6], m_[6], b_[6];

    #define LOADGRAY(arr, gy_)                                                     \
    do {                                                                           \
        int gy = (gy_);                                                            \
        gy = gy < 0 ? 0 : (gy > IMG_H - 1 ? IMG_H - 1 : gy);                       \
        size_t off = (size_t)gy * IMG_W + cx;                                      \
        float4 ra = *(const float4*)(rP + off);                                    \
        float4 ga = *(const float4*)(gP + off);                                    \
        float4 ba = *(const float4*)(bP + off);                                    \
        arr[1] = GRAY(ra.x, ga.x, ba.x); arr[2] = GRAY(ra.y, ga.y, ba.y);          \
        arr[3] = GRAY(ra.z, ga.z, ba.z); arr[4] = GRAY(ra.w, ga.w, ba.w);          \
        arr[0] = __shfl_up(arr[4], 1, 64);                                         \
        arr[5] = __shfl_down(arr[1], 1, 64);                                       \
        if (lane == 0)                                                             \
            arr[0] = half ? GRAY(rP[off - 1], gP[off - 1], bP[off - 1]) : arr[1];  \
        if (lane == 63)                                                            \
            arr[5] = half ? arr[4] : GRAY(rP[off + 4], gP[off + 4], bP[off + 4]);  \
    } while (0)

    // code = 2*code + (nei >= ctr), vcc-carry form (2 VALU per neighbor)
    #define LBPBIT(nei)                                                            \
        asm volatile("v_cmp_ge_f32 vcc, %1, %2\n\t"                                \
                     "v_addc_co_u32 %0, vcc, %0, %0, vcc"                          \
                     : "+v"(code) : "v"(nei), "v"(ctr) : "vcc")

    // OFFSETS bits: 1:(-1,-1) 2:(-1,0) 4:(-1,1) 8:(0,1) 16:(1,1) 32:(1,0)
    //               64:(1,-1) 128:(0,-1).  MSB-first Horner order below.
    #define COMPUTE4()                                                             \
    do {                                                                           \
        _Pragma("unroll")                                                          \
        for (int p = 0; p < 4; ++p) {                                              \
            const float ctr = m_[p + 1];                                           \
            unsigned code = 0u;                                                    \
            LBPBIT(m_[p    ]);   /* 128 */                                         \
            LBPBIT(b_[p    ]);   /*  64 */                                         \
            LBPBIT(b_[p + 1]);   /*  32 */                                         \
            LBPBIT(b_[p + 2]);   /*  16 */                                         \
            LBPBIT(m_[p + 2]);   /*   8 */                                         \
            LBPBIT(t_[p + 2]);   /*   4 */                                         \
            LBPBIT(t_[p + 1]);   /*   2 */                                         \
            LBPBIT(t_[p    ]);   /*   1 */                                         \
            atomicAdd(&lh[code], 1u);                                              \
        }                                                                          \
    } while (0)

    if ((strip & 1) == 0) {
        // walk top -> bottom
        LOADGRAY(t_, y0 - 1);
        LOADGRAY(m_, y0);
        #pragma unroll
        for (int i = 0; i < TSTRIP; ++i) {
            LOADGRAY(b_, y0 + 1 + i);
            COMPUTE4();
            #pragma unroll
            for (int k = 0; k < 6; ++k) { t_[k] = m_[k]; m_[k] = b_[k]; }
        }
    } else {
        // walk bottom -> top
        LOADGRAY(b_, y0 + TSTRIP);
        LOADGRAY(m_, y0 + TSTRIP - 1);
        #pragma unroll
        for (int i = 0; i < TSTRIP; ++i) {
            LOADGRAY(t_, y0 + TSTRIP - 2 - i);
            COMPUTE4();
            #pragma unroll
            for (int k = 0; k < 6; ++k) { b_[k] = m_[k]; m_[k] = t_[k]; }
        }
    }
    #undef LOADGRAY
    #undef LBPBIT
    #undef COMPUTE4

    __syncthreads();
    // plain-store partial histogram (overwrite each launch -> garbage-immune)
    part[((size_t)b * BLOCKS_PER_IMG + bg) * NBINS + tid] = (float)lh[tid];

    // ---- last block per image reduces + normalizes ----
    __threadfence();                             // make partial visible device-wide
    __shared__ unsigned int s_old;
    if (tid == 0)
        s_old = __hip_atomic_fetch_add(&cnt[b], 1u, __ATOMIC_ACQ_REL,
                                       __HIP_MEMORY_SCOPE_AGENT);
    __syncthreads();
    // Each launch adds exactly 16 to cnt[b]; for ANY initial value exactly one
    // block observes old % 16 == 15 -> it is the last finisher for image b.
    if ((s_old & 15u) == 15u) {
        float s = 0.0f;
        #pragma unroll
        for (int k = 0; k < BLOCKS_PER_IMG; ++k)
            s += part[((size_t)b * BLOCKS_PER_IMG + k) * NBINS + tid];
        float ssq = s * s;
        #pragma unroll
        for (int o = 32; o > 0; o >>= 1) ssq += __shfl_down(ssq, o, 64);
        __shared__ float wsum[4];
        if ((tid & 63) == 0) wsum[tid >> 6] = ssq;
        __syncthreads();
        float tot = wsum[0] + wsum[1] + wsum[2] + wsum[3];
        out[b * NBINS + tid] = s / (sqrtf(tot) + 1e-6f);
    }
}

extern "C" void kernel_launch(void* const* d_in, const int* in_sizes, int n_in,
                              void* d_out, int out_size, void* d_ws, size_t ws_size,
                              hipStream_t stream) {
    const float* x = (const float*)d_in[0];
    float* out = (float*)d_out;
    float* part = (float*)d_ws;                              // [64][16][256] floats
    unsigned int* cnt = (unsigned int*)((char*)d_ws +
                         (size_t)NBATCH * BLOCKS_PER_IMG * NBINS * sizeof(float));

    lbp_fused_kernel<<<NBLOCKS, 256, 0, stream>>>(x, part, cnt, out);
}

// Round 12
// 37.624 us; speedup vs baseline: 3.1621x; 3.1621x over previous
//
#include <hip/hip_runtime.h>

#define IMG_H 512
#define IMG_W 512
#define PLANE (IMG_H * IMG_W)
#define NBATCH 64
#define NBINS 256
#define TSTRIP 16                               // rows per strip
#define HALF_W 256                              // columns per wave (half strip)
#define WPB 4                                   // waves per block
#define BLOCKS_PER_IMG 16                       // 64 wave-tasks / 4
#define NBLOCKS (BLOCKS_PER_IMG * NBATCH)       // 1024 -> 4 blocks/CU, 16 waves/CU

#define GRAY(rr, gg, bb) (0.2989f * (rr) + 0.587f * (gg) + 0.114f * (bb))

// One wave walks a 16-row x 256-col half-strip, 4 px/lane, 3-row register ring.
// Snake walk + XCD swizzle. Seam column via 3 scalar loads on the edge lane.
// LBP code built MSB-first with v_cmp + v_addc (2 VALU per neighbor).
// Two-dispatch structure is deliberate: any in-kernel device-scope fence
// (threadfence / agent atomics / grid sync) invalidates per-XCD L2 and
// collapses streaming BW to ~600 GB/s (measured R6, R11).
__global__ __launch_bounds__(256) void lbp_strip_kernel(const float* __restrict__ x,
                                                        float* __restrict__ ws) {
    __shared__ unsigned int lh[NBINS];
    const int tid = threadIdx.x;
    lh[tid] = 0u;                                // 256 threads == 256 bins
    __syncthreads();

    // XCD swizzle: XCD = blockIdx.x % 8; sid groups 128 blocks (8 images) per XCD.
    const int lin = blockIdx.x;                  // 0..1023
    const int sid = (lin & 7) * (NBLOCKS / 8) + (lin >> 3);
    const int b   = sid >> 4;                    // image 0..63
    const int bg  = sid & 15;                    // block-group 0..15

    const int wav   = tid >> 6;                  // 0..3
    const int lane  = tid & 63;
    const int strip = bg * 2 + (wav >> 1);       // 0..31 (16-row strip)
    const int half  = wav & 1;                   // 0 = cols 0..255, 1 = 256..511
    const int y0    = strip * TSTRIP;

    const float* rP = x + (size_t)b * 3 * PLANE;
    const float* gP = rP + PLANE;
    const float* bP = rP + 2 * PLANE;
    const int    cx = half * HALF_W + 4 * lane;  // lane's first column

    // arr[0]=left neighbor (col cx-1), arr[1..4]=cols cx..cx+3, arr[5]=right (col cx+4)
    float t_[6], m_[6], b_[6];

    #define LOADGRAY(arr, gy_)                                                     \
    do {                                                                           \
        int gy = (gy_);                                                            \
        gy = gy < 0 ? 0 : (gy > IMG_H - 1 ? IMG_H - 1 : gy);                       \
        size_t off = (size_t)gy * IMG_W + cx;                                      \
        float4 ra = *(const float4*)(rP + off);                                    \
        float4 ga = *(const float4*)(gP + off);                                    \
        float4 ba = *(const float4*)(bP + off);                                    \
        arr[1] = GRAY(ra.x, ga.x, ba.x); arr[2] = GRAY(ra.y, ga.y, ba.y);          \
        arr[3] = GRAY(ra.z, ga.z, ba.z); arr[4] = GRAY(ra.w, ga.w, ba.w);          \
        arr[0] = __shfl_up(arr[4], 1, 64);                                         \
        arr[5] = __shfl_down(arr[1], 1, 64);                                       \
        if (lane == 0)                                                             \
            arr[0] = half ? GRAY(rP[off - 1], gP[off - 1], bP[off - 1]) : arr[1];  \
        if (lane == 63)                                                            \
            arr[5] = half ? arr[4] : GRAY(rP[off + 4], gP[off + 4], bP[off + 4]);  \
    } while (0)

    // code = 2*code + (nei >= ctr), vcc-carry form (2 VALU per neighbor)
    #define LBPBIT(nei)                                                            \
        asm volatile("v_cmp_ge_f32 vcc, %1, %2\n\t"                                \
                     "v_addc_co_u32 %0, vcc, %0, %0, vcc"                          \
                     : "+v"(code) : "v"(nei), "v"(ctr) : "vcc")

    // OFFSETS bits: 1:(-1,-1) 2:(-1,0) 4:(-1,1) 8:(0,1) 16:(1,1) 32:(1,0)
    //               64:(1,-1) 128:(0,-1).  MSB-first Horner order below.
    #define COMPUTE4()                                                             \
    do {                                                                           \
        _Pragma("unroll")                                                          \
        for (int p = 0; p < 4; ++p) {                                              \
            const float ctr = m_[p + 1];                                           \
            unsigned code = 0u;                                                    \
            LBPBIT(m_[p    ]);   /* 128 */                                         \
            LBPBIT(b_[p    ]);   /*  64 */                                         \
            LBPBIT(b_[p + 1]);   /*  32 */                                         \
            LBPBIT(b_[p + 2]);   /*  16 */                                         \
            LBPBIT(m_[p + 2]);   /*   8 */                                         \
            LBPBIT(t_[p + 2]);   /*   4 */                                         \
            LBPBIT(t_[p + 1]);   /*   2 */                                         \
            LBPBIT(t_[p    ]);   /*   1 */                                         \
            atomicAdd(&lh[code], 1u);                                              \
        }                                                                          \
    } while (0)

    if ((strip & 1) == 0) {
        // walk top -> bottom
        LOADGRAY(t_, y0 - 1);
        LOADGRAY(m_, y0);
        #pragma unroll
        for (int i = 0; i < TSTRIP; ++i) {
            LOADGRAY(b_, y0 + 1 + i);
            COMPUTE4();
            #pragma unroll
            for (int k = 0; k < 6; ++k) { t_[k] = m_[k]; m_[k] = b_[k]; }
        }
    } else {
        // walk bottom -> top
        LOADGRAY(b_, y0 + TSTRIP);
        LOADGRAY(m_, y0 + TSTRIP - 1);
        #pragma unroll
        for (int i = 0; i < TSTRIP; ++i) {
            LOADGRAY(t_, y0 + TSTRIP - 2 - i);
            COMPUTE4();
            #pragma unroll
            for (int k = 0; k < 6; ++k) { b_[k] = m_[k]; m_[k] = t_[k]; }
        }
    }
    #undef LOADGRAY
    #undef LBPBIT
    #undef COMPUTE4

    __syncthreads();
    // one partial histogram per block, no global atomics
    ws[((size_t)b * BLOCKS_PER_IMG + bg) * NBINS + tid] = (float)lh[tid];
}

// Sum the 16 partials per image, L2-normalize, write output.
__global__ __launch_bounds__(256) void finalize_kernel(const float* __restrict__ ws,
                                                       float* __restrict__ out) {
    const int b = blockIdx.x;
    const int t = threadIdx.x;
    float s = 0.0f;
    #pragma unroll
    for (int k = 0; k < BLOCKS_PER_IMG; ++k)
        s += ws[((size_t)b * BLOCKS_PER_IMG + k) * NBINS + t];
    float ss = s * s;
    #pragma unroll
    for (int o = 32; o > 0; o >>= 1) ss += __shfl_down(ss, o, 64);
    __shared__ float wsum[4];
    if ((t & 63) == 0) wsum[t >> 6] = ss;
    __syncthreads();
    float tot = wsum[0] + wsum[1] + wsum[2] + wsum[3];
    out[b * NBINS + t] = s / (sqrtf(tot) + 1e-6f);
}

extern "C" void kernel_launch(void* const* d_in, const int* in_sizes, int n_in,
                              void* d_out, int out_size, void* d_ws, size_t ws_size,
                              hipStream_t stream) {
    const float* x = (const float*)d_in[0];
    float* out = (float*)d_out;
    float* ws  = (float*)d_ws;   // 64 * 16 * 256 floats = 1 MB partial histograms

    lbp_strip_kernel<<<NBLOCKS, 256, 0, stream>>>(x, ws);
    finalize_kernel<<<NBATCH, 256, 0, stream>>>(ws, out);
}